// Round 9
// baseline (1681.585 us; speedup 1.0000x reference)
//
#include <hip/hip_runtime.h>
#include <hip/hip_bf16.h>

typedef __attribute__((ext_vector_type(8))) short short8v;
typedef __attribute__((ext_vector_type(4))) float float4v;

struct SedTab { signed char sgn[256]; signed char idx[256]; };

__device__ inline unsigned short f2bf(float f) {
    __hip_bfloat16 h = __float2bfloat16(f);
    return *reinterpret_cast<unsigned short*>(&h);
}

#define GLOAD_LDS16(g, l) __builtin_amdgcn_global_load_lds( \
    (const __attribute__((address_space(1))) void*)(g), \
    (__attribute__((address_space(3))) void*)(l), 16, 0, 0)

#define VMCNT(n) asm volatile("s_waitcnt vmcnt(" #n ")" ::: "memory")

// ---------------- Kernel P: build BigT (n-major) bf16 ----------------
__global__ __launch_bounds__(256) void build_bigT(
    const float* __restrict__ w_comp, unsigned short* __restrict__ bigT, SedTab tab)
{
    int e = blockIdx.x * 256 + threadIdx.x;
    if (e >= 1536 * 1536) return;
    int n = e / 1536, k = e - n * 1536;
    int t_out = n / 96, c = n - t_out * 96;
    int t_in = k / 96, m = k - t_in * 96;
    int i = tab.idx[t_in * 16 + t_out];
    float s = (float)tab.sgn[t_in * 16 + t_out];
    float v = s * w_comp[(i * 96 + m) * 96 + c];
    bigT[e] = f2bf(v);
}

// ---------------- Kernel W: window + cast to bf16 ----------------
__global__ __launch_bounds__(256) void window_cast(
    const float* __restrict__ x, unsigned short* __restrict__ xw)
{
    __shared__ unsigned short lds[96][260];
    int blk = blockIdx.x;
    int s1 = blk & 3, hh = (blk >> 2) & 63, b = blk >> 8;
    const float* src = x + (size_t)b * 6291456 + (size_t)(4 * hh + s1) * 256;

    for (int i = threadIdx.x; i < 6144; i += 256) {
        int m = i >> 6;
        int q = (i & 63) << 2;
        float4 v = *(const float4*)(src + (size_t)m * 65536 + q);
        lds[m][q + 0] = f2bf(v.x);
        lds[m][q + 1] = f2bf(v.y);
        lds[m][q + 2] = f2bf(v.z);
        lds[m][q + 3] = f2bf(v.w);
    }
    __syncthreads();
    size_t rowbase = (size_t)((b * 64 + hh) * 64) * 1536 + (size_t)s1 * 384;
    for (int i = threadIdx.x; i < 3072; i += 256) {
        int ww = i / 48, g = i - ww * 48;
        int s2 = g / 12, mg = (g - s2 * 12) * 8;
        int qq = 4 * ww + s2;
        short8v pk;
        #pragma unroll
        for (int j = 0; j < 8; ++j) pk[j] = (short)lds[mg + j][qq];
        *(short8v*)(xw + rowbase + (size_t)ww * 1536 + s2 * 96 + mg) = pk;
    }
}

// ---------------- Kernel G: 256x384 high-intensity GEMM + GELU + proj ----------------
// M=32768, K=1536. BM=256, BN=384, BK=64, 512 thr, 8 waves 2M x 4N,
// per-wave tile 128x96, acc[8][6] (192 regs). reads/MFMA = 0.292 KB (was
// 0.417) — the tile-ratio lever; schedule axis falsified R4-R8.
// Loop: { barA ; stage(kt+1 -> slot^1) ; VMCNT(10) [retire stage(kt), keep
// stage(kt+1) in flight] ; barB ; compute(kt) }. Counted, never drains until
// kt=23. WAR: stage(kt+1) overwrites slot last read by compute(kt-1), all
// waves past barA. RAW: barB after VMCNT(10) -> every wave's stage(kt) landed.
// LDS: 2 slots x (A 32KB + B 48KB) = 160 KB exact. XOR involution swizzle
// (verified 0-conflict R4-R8). Epilogue: 2 halves x {GELU->yl (XOR'd cols,
// fixes R7/R8's 2.5M write conflicts), proj MFMA, coalesced NCHW store}.
__global__ __launch_bounds__(512, 2) void gemm_fused(
    const unsigned short* __restrict__ A,
    const unsigned short* __restrict__ Bt,
    const float* __restrict__ pw, const float* __restrict__ pb,
    float* __restrict__ out)
{
    __shared__ __attribute__((aligned(16))) char smem[163840];
    const int t = threadIdx.x;
    const int lane = t & 63, w = t >> 6;
    const int wm = w >> 2, wn = w & 3;           // 2M x 4N
    const int lr = lane & 15, lg = lane >> 4;

    // XCD-aware bijective swizzle: 512 blocks = 8 XCDs x 64, nt slow
    const int bid = blockIdx.x;
    const int wg = (bid & 7) * 64 + (bid >> 3);
    const int nt = wg >> 7, mt = wg & 127;       // 4 nt x 128 mt
    const int m0 = mt * 256, n0 = nt * 384;

    float4v acc[8][6];
    #pragma unroll
    for (int i = 0; i < 8; ++i)
        #pragma unroll
        for (int j = 0; j < 6; ++j) acc[i][j] = (float4v)0.0f;

    // staging: chunk c = t + i*512 -> row rA + 64*i, kc const across i
    const int rA = t >> 3;
    const int kc = ((t & 7) ^ (rA & 7)) << 3;
    const unsigned short* gA = A  + (size_t)(m0 + rA) * 1536 + kc;
    const unsigned short* gB = Bt + (size_t)(n0 + rA) * 1536 + kc;
    const int dst = t * 16;

    auto stage = [&](int slot, int ko) {   // A 256x64 (4 loads) + B 384x64 (6)
        char* sa = smem + slot * 81920;
        char* sb = sa + 32768;
        #pragma unroll
        for (int i = 0; i < 4; ++i)
            GLOAD_LDS16(gA + ko + (size_t)i * 64 * 1536, sa + dst + i * 8192);
        #pragma unroll
        for (int i = 0; i < 6; ++i)
            GLOAD_LDS16(gB + ko + (size_t)i * 64 * 1536, sb + dst + i * 8192);
    };

    // prologue
    stage(0, 0);

    const int c0 = (lg * 8) ^ ((lr & 7) << 3);       // ks0 col (elems)
    const int c1 = (32 + lg * 8) ^ ((lr & 7) << 3);  // ks1 col
    const int ar = wm * 128 + lr;                    // + mf*16
    const int br = wn * 96 + lr;                     // + nf*16

    for (int kt = 0; kt < 24; ++kt) {
        __builtin_amdgcn_s_barrier();                // barA: prev compute done
        __builtin_amdgcn_sched_barrier(0);
        if (kt < 23) stage((kt + 1) & 1, (kt + 1) * 64);
        if (kt < 23)       { VMCNT(10); }            // retire stage(kt)
        else               { VMCNT(0); }
        __builtin_amdgcn_s_barrier();                // barB: slot[kt&1] ready
        __builtin_amdgcn_sched_barrier(0);

        const unsigned short* as = (const unsigned short*)(smem + (kt & 1) * 81920);
        const unsigned short* bs = as + 16384;       // +32768 B

        #pragma unroll
        for (int ks = 0; ks < 2; ++ks) {
            const int ck = ks ? c1 : c0;
            short8v a[8];
            #pragma unroll
            for (int mf = 0; mf < 8; ++mf)
                a[mf] = *(const short8v*)(as + (ar + mf * 16) * 64 + ck);
            __builtin_amdgcn_s_setprio(1);
            #pragma unroll
            for (int nf = 0; nf < 6; ++nf) {
                short8v b = *(const short8v*)(bs + (br + nf * 16) * 64 + ck);
                #pragma unroll
                for (int mf = 0; mf < 8; ++mf)
                    acc[mf][nf] = __builtin_amdgcn_mfma_f32_16x16x32_bf16(
                        a[mf], b, acc[mf][nf], 0, 0, 0);
            }
            __builtin_amdgcn_s_setprio(0);
        }
    }

    // ================= fused epilogue (2 halves of 512 pos) =================
    unsigned short* yl  = (unsigned short*)smem;            // [512][104]
    unsigned short* pwl = (unsigned short*)(smem + 106496); // [96][104]
    float*          pbl = (float*)(smem + 126464);          // [96]

    const int b  = mt >> 4;
    const int hh_base = (mt & 15) * 4;
    const int posr = w * 64 + lr;

    __syncthreads();   // main-loop LDS reads done; smem reused

    // pw/pb staged once (all threads), concurrent with half-0 yl fill
    for (int i = t; i < 9216; i += 512) {
        int r = i / 96, c = i - r * 96;
        pwl[r * 104 + c] = f2bf(pw[i]);
    }
    if (t < 96) pbl[t] = pb[t];

    #pragma unroll
    for (int h = 0; h < 2; ++h) {
        if (h == 1) __syncthreads();   // half-0 proj reads done before refill
        if (wm == h) {
            #pragma unroll
            for (int mf = 0; mf < 8; ++mf) {
                #pragma unroll
                for (int r = 0; r < 4; ++r) {
                    const int l = mf * 16 + lg * 4 + r;           // 0..127
                    const int pos = (l >> 6) * 256 + 4 * (l & 63) + wn;
                    const int key = (pos >> 4) & 3;
                    #pragma unroll
                    for (int nf = 0; nf < 6; ++nf) {
                        const int c = nf * 16 + lr;
                        const int col = (c & 7) + 8 * ((c >> 3) ^ key);
                        float v = acc[mf][nf][r];
                        float g = 0.5f * v * (1.0f + erff(v * 0.70710678118654752f));
                        yl[pos * 104 + col] = f2bf(g);
                    }
                }
            }
        }
        __syncthreads();

        float4v pacc[6][4];
        #pragma unroll
        for (int i = 0; i < 6; ++i)
            #pragma unroll
            for (int j = 0; j < 4; ++j) pacc[i][j] = (float4v)0.0f;

        #pragma unroll
        for (int ks2 = 0; ks2 < 3; ++ks2) {
            const int ck = ks2 * 32 + lg * 8;
            short8v pf[6], yf[4];
            #pragma unroll
            for (int mf2 = 0; mf2 < 6; ++mf2)
                pf[mf2] = *(const short8v*)(pwl + (mf2 * 16 + lr) * 104 + ck);
            #pragma unroll
            for (int nf2 = 0; nf2 < 4; ++nf2) {
                const int col = (ck & 7) + 8 * (((ck >> 3)) ^ nf2); // key=nf2
                yf[nf2] = *(const short8v*)(yl + (posr + nf2 * 16) * 104 + col);
            }
            #pragma unroll
            for (int mf2 = 0; mf2 < 6; ++mf2)
                #pragma unroll
                for (int nf2 = 0; nf2 < 4; ++nf2)
                    pacc[mf2][nf2] = __builtin_amdgcn_mfma_f32_16x16x32_bf16(
                        pf[mf2], yf[nf2], pacc[mf2][nf2], 0, 0, 0);
        }

        const int p = 4 * (hh_base + 2 * h + (w >> 2)) + nt;
        const size_t obase = (size_t)b * 6291456 + (size_t)p * 256;
        #pragma unroll
        for (int mf2 = 0; mf2 < 6; ++mf2) {
            #pragma unroll
            for (int r = 0; r < 4; ++r) {
                const int co = mf2 * 16 + lg * 4 + r;
                const float bias = pbl[co];
                #pragma unroll
                for (int nf2 = 0; nf2 < 4; ++nf2) {
                    const int q = (w & 3) * 64 + nf2 * 16 + lr;
                    out[obase + (size_t)co * 65536 + q] = pacc[mf2][nf2][r] + bias;
                }
            }
        }
    }
}

// ---------------- host: Cayley-Dickson table ----------------
static void cd_table(int n, int* S, int* K) {
    if (n == 1) { S[0] = 1; K[0] = 0; return; }
    int m = n / 2;
    int s[64], k[64];
    cd_table(m, s, k);
    for (int i = 0; i < n; ++i) {
        for (int j = 0; j < n; ++j) {
            if (i < m && j < m) { S[i*n+j] = s[i*m+j]; K[i*n+j] = k[i*m+j]; }
            else if (i < m) { int q = j - m; S[i*n+j] = s[q*m+i]; K[i*n+j] = m + k[q*m+i]; }
            else if (j < m) { int p = i - m; int cj = (j == 0) ? 1 : -1;
                              S[i*n+j] = s[p*m+j] * cj; K[i*n+j] = m + k[p*m+j]; }
            else { int p = i - m, q = j - m; int cq = (q == 0) ? 1 : -1;
                   S[i*n+j] = -cq * s[q*m+p]; K[i*n+j] = k[q*m+p]; }
        }
    }
}

extern "C" void kernel_launch(void* const* d_in, const int* in_sizes, int n_in,
                              void* d_out, int out_size, void* d_ws, size_t ws_size,
                              hipStream_t stream) {
    const float* x      = (const float*)d_in[0];
    const float* w_comp = (const float*)d_in[1];
    const float* proj_w = (const float*)d_in[2];
    const float* proj_b = (const float*)d_in[3];
    float* out = (float*)d_out;

    // ws layout: Xw bf16 (100,663,296 B) | BigT bf16 (4,718,592 B)
    unsigned short* Xw   = (unsigned short*)d_ws;
    unsigned short* BigT = (unsigned short*)((char*)d_ws + 100663296);

    int S16[256], K16[256];
    cd_table(16, S16, K16);
    SedTab tab;
    for (int i = 0; i < 16; ++i)
        for (int j = 0; j < 16; ++j) {
            int k = K16[i * 16 + j];
            tab.idx[j * 16 + k] = (signed char)i;
            tab.sgn[j * 16 + k] = (signed char)S16[i * 16 + j];
        }

    hipLaunchKernelGGL(build_bigT, dim3(9216), dim3(256), 0, stream, w_comp, BigT, tab);
    hipLaunchKernelGGL(window_cast, dim3(2048), dim3(256), 0, stream, x, Xw);
    hipLaunchKernelGGL(gemm_fused, dim3(512), dim3(512), 0, stream,
                       Xw, BigT, proj_w, proj_b, out);
}

// Round 10
// 293.638 us; speedup vs baseline: 5.7267x; 5.7267x over previous
//
#include <hip/hip_runtime.h>
#include <hip/hip_bf16.h>

typedef __attribute__((ext_vector_type(8))) short short8v;
typedef __attribute__((ext_vector_type(4))) float float4v;

struct SedTab { signed char sgn[256]; signed char idx[256]; };

__device__ inline unsigned short f2bf(float f) {
    __hip_bfloat16 h = __float2bfloat16(f);
    return *reinterpret_cast<unsigned short*>(&h);
}

#define GLOAD_LDS16(g, l) __builtin_amdgcn_global_load_lds( \
    (const __attribute__((address_space(1))) void*)(g), \
    (__attribute__((address_space(3))) void*)(l), 16, 0, 0)

#define VMCNT(n) asm volatile("s_waitcnt vmcnt(" #n ")" ::: "memory")

// ---------------- Kernel P: build BigT (n-major) bf16 ----------------
__global__ __launch_bounds__(256) void build_bigT(
    const float* __restrict__ w_comp, unsigned short* __restrict__ bigT, SedTab tab)
{
    int e = blockIdx.x * 256 + threadIdx.x;
    if (e >= 1536 * 1536) return;
    int n = e / 1536, k = e - n * 1536;
    int t_out = n / 96, c = n - t_out * 96;
    int t_in = k / 96, m = k - t_in * 96;
    int i = tab.idx[t_in * 16 + t_out];
    float s = (float)tab.sgn[t_in * 16 + t_out];
    float v = s * w_comp[(i * 96 + m) * 96 + c];
    bigT[e] = f2bf(v);
}

// ---------------- Kernel W: window + cast to bf16 ----------------
__global__ __launch_bounds__(256) void window_cast(
    const float* __restrict__ x, unsigned short* __restrict__ xw)
{
    __shared__ unsigned short lds[96][260];
    int blk = blockIdx.x;
    int s1 = blk & 3, hh = (blk >> 2) & 63, b = blk >> 8;
    const float* src = x + (size_t)b * 6291456 + (size_t)(4 * hh + s1) * 256;

    for (int i = threadIdx.x; i < 6144; i += 256) {
        int m = i >> 6;
        int q = (i & 63) << 2;
        float4 v = *(const float4*)(src + (size_t)m * 65536 + q);
        lds[m][q + 0] = f2bf(v.x);
        lds[m][q + 1] = f2bf(v.y);
        lds[m][q + 2] = f2bf(v.z);
        lds[m][q + 3] = f2bf(v.w);
    }
    __syncthreads();
    size_t rowbase = (size_t)((b * 64 + hh) * 64) * 1536 + (size_t)s1 * 384;
    for (int i = threadIdx.x; i < 3072; i += 256) {
        int ww = i / 48, g = i - ww * 48;
        int s2 = g / 12, mg = (g - s2 * 12) * 8;
        int qq = 4 * ww + s2;
        short8v pk;
        #pragma unroll
        for (int j = 0; j < 8; ++j) pk[j] = (short)lds[mg + j][qq];
        *(short8v*)(xw + rowbase + (size_t)ww * 1536 + s2 * 96 + mg) = pk;
    }
}

// ---------------- Kernel G: fused GEMM + GELU + projection (R5 discipline) ----------------
// M=32768, K=1536. BM=128, BN=384, BK=64, 512 thr, 8 waves 2M x 4N,
// wave tile 64x96, acc[4][6] (96 AGPR, ~110 VGPR — known-good R7 budget).
// R5-exact phase shape (the 200us structure): per phase
//   { ds_reads(this phase's MFMA) ; stage pair ; sched_barrier ; s_barrier ;
//     setprio(1) 12 MFMA setprio(0) }   (ONE barrier per phase)
// Stages: ph0/1/2 = B(kt+1) pairs, ph3 = A(kt+2) pair + gate VMCNT(2)
// (retires A(kt+1)+B(kt+1), leaves A(kt+2)'s 2 in flight). VMCNT(0) @ kt=22.
// WAR: stage target slot's last readers finished >=2 barriers earlier (3-slot
// A / 2-slot B rotation). RAW: gate one full kt before first read.
// XCD swizzle, mt-fast: mt = xcd*32 + (c>>2), nt = c&3 -> an A-tile's 4
// nt-siblings run concurrently on the SAME XCD => A served from that L2
// (was: different XCDs => L3/HBM re-fetch; FETCH 216 MB).
// LDS: A 3 slots (16KB), B 2 slots (48KB) = 144KB; epilogue reuses smem.
// XOR involution swizzle both sides (rule #21), verified 0 conflicts R4-R8.
__global__ __launch_bounds__(512, 2) void gemm_fused(
    const unsigned short* __restrict__ A,
    const unsigned short* __restrict__ Bt,
    const float* __restrict__ pw, const float* __restrict__ pb,
    float* __restrict__ out)
{
    __shared__ __attribute__((aligned(16))) char smem[147456];
    const int t = threadIdx.x;
    const int lane = t & 63, w = t >> 6;
    const int wm = w >> 2, wn = w & 3;           // 2M x 4N
    const int lr = lane & 15, lg = lane >> 4;

    // XCD-aware swizzle, mt-fast within XCD chunk (A-tile L2 co-location)
    const int bid = blockIdx.x;
    const int xc = bid & 7, cc = bid >> 3;       // 8 XCDs x 128 chunks
    const int mt = xc * 32 + (cc >> 2);          // [0,256)
    const int nt = cc & 3;                       // [0,4)
    const int m0 = mt * 128, n0 = nt * 384;

    float4v acc[4][6];
    #pragma unroll
    for (int i = 0; i < 4; ++i)
        #pragma unroll
        for (int j = 0; j < 6; ++j) acc[i][j] = (float4v)0.0f;

    // staging bases: chunk c = t + i*512 -> row (c>>3) = rA + i*64; kchunk
    // (c&7)^(row&7) constant across i (64 ≡ 0 mod 8).
    const int rA = t >> 3;
    const int kc = ((t & 7) ^ (rA & 7)) << 3;
    const unsigned short* gA = A  + (size_t)(m0 + rA) * 1536 + kc;
    const unsigned short* gB = Bt + (size_t)(n0 + rA) * 1536 + kc;
    const int dst = t * 16;

    auto stageA = [&](char* s, int ko) {         // 128x64 tile: 2 loads
        GLOAD_LDS16(gA + ko,             s + dst);
        GLOAD_LDS16(gA + ko + 64 * 1536, s + dst + 8192);
    };
    auto stageB2 = [&](char* s, int ko, int i) { // pair i of 3 (384x64 tile)
        GLOAD_LDS16(gB + ko + (size_t)(2 * i)     * 64 * 1536, s + dst + (2 * i)     * 8192);
        GLOAD_LDS16(gB + ko + (size_t)(2 * i + 1) * 64 * 1536, s + dst + (2 * i + 1) * 8192);
    };

    char* a_rd = smem;          char* a_md = smem + 16384; char* a_wr = smem + 32768;
    char* b_rd = smem + 49152;  char* b_wr = smem + 98304;

    // prologue: A0(2), B0(6), A1(2); gate VMCNT(2) = A0,B0 landed, A1 in flight
    stageA(a_rd, 0);
    stageB2(b_rd, 0, 0); stageB2(b_rd, 0, 1); stageB2(b_rd, 0, 2);
    stageA(a_md, 64);
    VMCNT(2);
    __builtin_amdgcn_s_barrier();

    const int c0 = (lg * 8) ^ ((lr & 7) << 3);       // ks0 col (elems)
    const int c1 = (32 + lg * 8) ^ ((lr & 7) << 3);  // ks1 col
    const int ar = wm * 64 + lr;                     // + mf*16
    const int br = wn * 96 + lr;                     // + nf*16

    short8v aE[4], aO[4], b0[3], b1[3], b2[3], b3[3];

    int koB = 64, koA = 128;
    for (int kt = 0; kt < 24; ++kt) {
        const unsigned short* as = (const unsigned short*)a_rd;
        const unsigned short* bs = (const unsigned short*)b_rd;

        // ---- ph0: read aE+b0 | stage B(kt+1) pair0 | bar | MFMA ----
        #pragma unroll
        for (int mf = 0; mf < 4; ++mf) aE[mf] = *(const short8v*)(as + (ar + mf * 16) * 64 + c0);
        #pragma unroll
        for (int j = 0; j < 3; ++j)    b0[j]  = *(const short8v*)(bs + (br + j * 16) * 64 + c0);
        if (kt < 23) stageB2(b_wr, koB, 0);
        __builtin_amdgcn_sched_barrier(0);
        __builtin_amdgcn_s_barrier();
        __builtin_amdgcn_s_setprio(1);
        #pragma unroll
        for (int mf = 0; mf < 4; ++mf)
            #pragma unroll
            for (int nf = 0; nf < 3; ++nf)
                acc[mf][nf] = __builtin_amdgcn_mfma_f32_16x16x32_bf16(
                    aE[mf], b0[nf], acc[mf][nf], 0, 0, 0);
        __builtin_amdgcn_s_setprio(0);

        // ---- ph1: read b1 | stage B(kt+1) pair1 | bar | MFMA ----
        #pragma unroll
        for (int j = 0; j < 3; ++j) b1[j] = *(const short8v*)(bs + (br + (3 + j) * 16) * 64 + c0);
        if (kt < 23) stageB2(b_wr, koB, 1);
        __builtin_amdgcn_sched_barrier(0);
        __builtin_amdgcn_s_barrier();
        __builtin_amdgcn_s_setprio(1);
        #pragma unroll
        for (int mf = 0; mf < 4; ++mf)
            #pragma unroll
            for (int nf = 0; nf < 3; ++nf)
                acc[mf][3 + nf] = __builtin_amdgcn_mfma_f32_16x16x32_bf16(
                    aE[mf], b1[nf], acc[mf][3 + nf], 0, 0, 0);
        __builtin_amdgcn_s_setprio(0);

        // ---- ph2: read aO+b2 | stage B(kt+1) pair2 | bar | MFMA ----
        #pragma unroll
        for (int mf = 0; mf < 4; ++mf) aO[mf] = *(const short8v*)(as + (ar + mf * 16) * 64 + c1);
        #pragma unroll
        for (int j = 0; j < 3; ++j)    b2[j]  = *(const short8v*)(bs + (br + j * 16) * 64 + c1);
        if (kt < 23) stageB2(b_wr, koB, 2);
        __builtin_amdgcn_sched_barrier(0);
        __builtin_amdgcn_s_barrier();
        __builtin_amdgcn_s_setprio(1);
        #pragma unroll
        for (int mf = 0; mf < 4; ++mf)
            #pragma unroll
            for (int nf = 0; nf < 3; ++nf)
                acc[mf][nf] = __builtin_amdgcn_mfma_f32_16x16x32_bf16(
                    aO[mf], b2[nf], acc[mf][nf], 0, 0, 0);
        __builtin_amdgcn_s_setprio(0);

        // ---- ph3: read b3 | stage A(kt+2) | gate | bar | MFMA ----
        #pragma unroll
        for (int j = 0; j < 3; ++j) b3[j] = *(const short8v*)(bs + (br + (3 + j) * 16) * 64 + c1);
        if (kt < 22) stageA(a_wr, koA);
        if (kt < 22)       { VMCNT(2); }
        else if (kt == 22) { VMCNT(0); }
        __builtin_amdgcn_sched_barrier(0);
        __builtin_amdgcn_s_barrier();
        __builtin_amdgcn_s_setprio(1);
        #pragma unroll
        for (int mf = 0; mf < 4; ++mf)
            #pragma unroll
            for (int nf = 0; nf < 3; ++nf)
                acc[mf][3 + nf] = __builtin_amdgcn_mfma_f32_16x16x32_bf16(
                    aO[mf], b3[nf], acc[mf][3 + nf], 0, 0, 0);
        __builtin_amdgcn_s_setprio(0);

        char* tmp = a_rd; a_rd = a_md; a_md = a_wr; a_wr = tmp;
        tmp = b_rd; b_rd = b_wr; b_wr = tmp;
        koB += 64; koA += 64;
    }

    // ================= fused epilogue =================
    __syncthreads();   // all main-loop LDS reads done; smem reused below

    unsigned short* yl  = (unsigned short*)smem;            // [512][104] bf16
    unsigned short* pwl = (unsigned short*)(smem + 106496); // [96][104] bf16
    float*          pbl = (float*)(smem + 126464);          // [96] f32

    for (int i = t; i < 9216; i += 512) {
        int r = i / 96, c = i - r * 96;
        pwl[r * 104 + c] = f2bf(pw[i]);
    }
    if (t < 96) pbl[t] = pb[t];

    // GELU + write yl: pos = wm*256 + 4*ww + wn (q-major), c = nf*16+lr
    #pragma unroll
    for (int mf = 0; mf < 4; ++mf) {
        #pragma unroll
        for (int r = 0; r < 4; ++r) {
            const int ww = mf * 16 + lg * 4 + r;
            const int pos = wm * 256 + 4 * ww + wn;
            #pragma unroll
            for (int nf = 0; nf < 6; ++nf) {
                float v = acc[mf][nf][r];
                float g = 0.5f * v * (1.0f + erff(v * 0.70710678118654752f));
                yl[pos * 104 + nf * 16 + lr] = f2bf(g);
            }
        }
    }
    __syncthreads();

    // proj MFMA: D[c_out][pos], A-frag = pwl rows (c_out), B-frag = yl rows (pos)
    float4v pacc[6][4];
    #pragma unroll
    for (int i = 0; i < 6; ++i)
        #pragma unroll
        for (int j = 0; j < 4; ++j) pacc[i][j] = (float4v)0.0f;

    const int posr = w * 64 + lr;   // + nf2*16
    #pragma unroll
    for (int ks = 0; ks < 3; ++ks) {
        const int ck = ks * 32 + lg * 8;
        short8v pf[6], yf[4];
        #pragma unroll
        for (int mf2 = 0; mf2 < 6; ++mf2)
            pf[mf2] = *(const short8v*)(pwl + (mf2 * 16 + lr) * 104 + ck);
        #pragma unroll
        for (int nf2 = 0; nf2 < 4; ++nf2)
            yf[nf2] = *(const short8v*)(yl + (posr + nf2 * 16) * 104 + ck);
        #pragma unroll
        for (int mf2 = 0; mf2 < 6; ++mf2)
            #pragma unroll
            for (int nf2 = 0; nf2 < 4; ++nf2)
                pacc[mf2][nf2] = __builtin_amdgcn_mfma_f32_16x16x32_bf16(
                    pf[mf2], yf[nf2], pacc[mf2][nf2], 0, 0, 0);
    }

    // store: rows mt*128.. = (b, hh = (mt&31)*2 + hh2); p = 4*hh + nt; q = pos&255
    const int b  = mt >> 5;
    const int hh = (mt & 31) * 2 + (w >> 2);
    const int p  = 4 * hh + nt;
    const size_t obase = (size_t)b * 6291456 + (size_t)p * 256;
    #pragma unroll
    for (int mf2 = 0; mf2 < 6; ++mf2) {
        #pragma unroll
        for (int r = 0; r < 4; ++r) {
            const int co = mf2 * 16 + lg * 4 + r;
            const float bias = pbl[co];
            #pragma unroll
            for (int nf2 = 0; nf2 < 4; ++nf2) {
                const int q = (w & 3) * 64 + nf2 * 16 + lr;
                out[obase + (size_t)co * 65536 + q] = pacc[mf2][nf2][r] + bias;
            }
        }
    }
}

// ---------------- host: Cayley-Dickson table ----------------
static void cd_table(int n, int* S, int* K) {
    if (n == 1) { S[0] = 1; K[0] = 0; return; }
    int m = n / 2;
    int s[64], k[64];
    cd_table(m, s, k);
    for (int i = 0; i < n; ++i) {
        for (int j = 0; j < n; ++j) {
            if (i < m && j < m) { S[i*n+j] = s[i*m+j]; K[i*n+j] = k[i*m+j]; }
            else if (i < m) { int q = j - m; S[i*n+j] = s[q*m+i]; K[i*n+j] = m + k[q*m+i]; }
            else if (j < m) { int p = i - m; int cj = (j == 0) ? 1 : -1;
                              S[i*n+j] = s[p*m+j] * cj; K[i*n+j] = m + k[p*m+j]; }
            else { int p = i - m, q = j - m; int cq = (q == 0) ? 1 : -1;
                   S[i*n+j] = -cq * s[q*m+p]; K[i*n+j] = k[q*m+p]; }
        }
    }
}

extern "C" void kernel_launch(void* const* d_in, const int* in_sizes, int n_in,
                              void* d_out, int out_size, void* d_ws, size_t ws_size,
                              hipStream_t stream) {
    const float* x      = (const float*)d_in[0];
    const float* w_comp = (const float*)d_in[1];
    const float* proj_w = (const float*)d_in[2];
    const float* proj_b = (const float*)d_in[3];
    float* out = (float*)d_out;

    // ws layout: Xw bf16 (100,663,296 B) | BigT bf16 (4,718,592 B)
    unsigned short* Xw   = (unsigned short*)d_ws;
    unsigned short* BigT = (unsigned short*)((char*)d_ws + 100663296);

    int S16[256], K16[256];
    cd_table(16, S16, K16);
    SedTab tab;
    for (int i = 0; i < 16; ++i)
        for (int j = 0; j < 16; ++j) {
            int k = K16[i * 16 + j];
            tab.idx[j * 16 + k] = (signed char)i;
            tab.sgn[j * 16 + k] = (signed char)S16[i * 16 + j];
        }

    hipLaunchKernelGGL(build_bigT, dim3(9216), dim3(256), 0, stream, w_comp, BigT, tab);
    hipLaunchKernelGGL(window_cast, dim3(2048), dim3(256), 0, stream, x, Xw);
    hipLaunchKernelGGL(gemm_fused, dim3(1024), dim3(512), 0, stream,
                       Xw, BigT, proj_w, proj_b, out);
}